// Round 1
// baseline (9370.384 us; speedup 1.0000x reference)
//
#include <hip/hip_runtime.h>
#include <math.h>

// ---- problem dims ----
constexpr int NB   = 32;     // batch
constexpr int NS   = 256;    // seq len
constexpr int NLC  = 16;     // chars per word
constexpr int NWD  = 256;    // word dim
constexpr int NCD  = 124;    // char dim
constexpr int NCO  = 32;     // cnn out
constexpr int NPOS = 36;
constexpr int NENR = 7;
constexpr int NH   = 512;    // lstm hidden
constexpr int NT   = 18;     // tags
constexpr int NIN0 = 331;    // 256+36+32+7
constexpr int NIN0P= 336;    // padded to x16
constexpr int NIN1 = 1024;
constexpr int NBS  = NB*NS;  // 8192
constexpr int NG4  = 4*NH;   // 2048
constexpr int NHID = 128;

__device__ __forceinline__ float sigmoidf_(float x){ return 1.0f/(1.0f+expf(-x)); }

// ---------------- features: word embed + char CNN + concat + relu ----------------
__global__ __launch_bounds__(128) void k_features(const int* __restrict__ x_word,
    const float* __restrict__ x_pos, const int* __restrict__ x_char,
    const float* __restrict__ x_enr, const float* __restrict__ wembW,
    const float* __restrict__ cembW, const float* __restrict__ cnnW,
    const float* __restrict__ cnnb, float* __restrict__ xout)
{
    __shared__ float ce[NLC][NCD];
    __shared__ float cv[NCO][13];
    __shared__ float cpool[NCO];
    int n = blockIdx.x;
    int tid = threadIdx.x;
    for (int i = tid; i < NLC*NCD; i += 128) {
        int l = i / NCD, c = i % NCD;
        ce[l][c] = cembW[x_char[n*NLC + l]*NCD + c];
    }
    __syncthreads();
    // 384 (o,t) pairs; o = p&31 so each thread keeps same o across its 3 pairs
    for (int p = tid; p < NCO*12; p += 128) {
        int o = p & 31, t = p >> 5;
        const float* wr = cnnW + o*NCD*5;
        float acc = 0.f;
        for (int c = 0; c < NCD; c++) {
            #pragma unroll
            for (int k = 0; k < 5; k++) acc += ce[t+k][c] * wr[c*5+k];
        }
        cv[o][t] = acc;
    }
    __syncthreads();
    if (tid < NCO) {
        float m = cv[tid][0];
        #pragma unroll
        for (int t = 1; t < 12; t++) m = fmaxf(m, cv[tid][t]);
        cpool[tid] = m + cnnb[tid];
    }
    __syncthreads();
    int widx = x_word[n];
    float* xr = xout + (size_t)n * NIN0P;
    for (int j = tid; j < NIN0P; j += 128) {
        float v;
        if (j < NWD)            v = wembW[(size_t)widx*NWD + j];
        else if (j < NWD+NPOS)  v = x_pos[n*NPOS + (j-NWD)];
        else if (j < NWD+NPOS+NCO) v = cpool[j-(NWD+NPOS)];
        else if (j < NIN0)      v = x_enr[n*NENR + (j-(NWD+NPOS+NCO))];
        else                    v = 0.f;   // K pad
        xr[j] = fmaxf(v, 0.f);
    }
}

// ---------------- pad layer-0 Wih from K=331 to K=336 (zero tail) ----------------
__global__ void k_pad_wih(const float* __restrict__ Wf, const float* __restrict__ Wb,
                          float* __restrict__ Pf, float* __restrict__ Pb)
{
    const float* Wsrc = blockIdx.y ? Wb : Wf;
    float* Pdst = blockIdx.y ? Pb : Pf;
    int i = blockIdx.x*256 + threadIdx.x;
    if (i < NG4*NIN0P) {
        int r = i / NIN0P, c = i % NIN0P;
        Pdst[i] = (c < NIN0) ? Wsrc[r*NIN0 + c] : 0.f;
    }
}

// ---------------- f32 GEMM: C[M,N] = A[M,K] @ W[N,K]^T + bias[N] ----------------
// 128x128 tile, BK=16, 256 threads, 8x8 micro. K must be a multiple of 16, M,N of 128 (N=128 ok).
constexpr int GBM = 128, GBN = 128, GBK = 16;
__global__ __launch_bounds__(256) void k_gemm(const float* __restrict__ A,
    const float* __restrict__ W, const float* __restrict__ bias,
    float* __restrict__ C, int M, int N, int K)
{
    __shared__ float As[GBK][GBM+4];
    __shared__ float Bs[GBK][GBN+4];
    int bm = blockIdx.x * GBM, bn = blockIdx.y * GBN;
    int tid = threadIdx.x;
    int tm = (tid & 15) * 8, tn = (tid >> 4) * 8;
    float acc[8][8] = {};
    for (int k0 = 0; k0 < K; k0 += GBK) {
        #pragma unroll
        for (int ii = 0; ii < 2; ii++) {
            int idx = tid + 256*ii;          // 0..511
            int m = idx >> 2, kj = (idx & 3) * 4;
            float4 va = *(const float4*)(A + (size_t)(bm+m)*K + k0 + kj);
            As[kj+0][m] = va.x; As[kj+1][m] = va.y; As[kj+2][m] = va.z; As[kj+3][m] = va.w;
            float4 vb = *(const float4*)(W + (size_t)(bn+m)*K + k0 + kj);
            Bs[kj+0][m] = vb.x; Bs[kj+1][m] = vb.y; Bs[kj+2][m] = vb.z; Bs[kj+3][m] = vb.w;
        }
        __syncthreads();
        #pragma unroll
        for (int k = 0; k < GBK; k++) {
            float a[8], b[8];
            *(float4*)&a[0] = *(const float4*)&As[k][tm];
            *(float4*)&a[4] = *(const float4*)&As[k][tm+4];
            *(float4*)&b[0] = *(const float4*)&Bs[k][tn];
            *(float4*)&b[4] = *(const float4*)&Bs[k][tn+4];
            #pragma unroll
            for (int i = 0; i < 8; i++)
                #pragma unroll
                for (int j = 0; j < 8; j++)
                    acc[i][j] += a[i]*b[j];
        }
        __syncthreads();
    }
    #pragma unroll
    for (int i = 0; i < 8; i++) {
        float4 o0, o1;
        o0.x = acc[i][0]+bias[bn+tn+0]; o0.y = acc[i][1]+bias[bn+tn+1];
        o0.z = acc[i][2]+bias[bn+tn+2]; o0.w = acc[i][3]+bias[bn+tn+3];
        o1.x = acc[i][4]+bias[bn+tn+4]; o1.y = acc[i][5]+bias[bn+tn+5];
        o1.z = acc[i][6]+bias[bn+tn+6]; o1.w = acc[i][7]+bias[bn+tn+7];
        *(float4*)(C + (size_t)(bm+tm+i)*N + bn+tn)   = o0;
        *(float4*)(C + (size_t)(bm+tm+i)*N + bn+tn+4) = o1;
    }
}

// ---------------- one LSTM timestep, both directions ----------------
// grid (128, 2): blockIdx.x = 4-hidden-unit chunk (16 gate rows), blockIdx.y = dir.
// z = zx[b,t_eff,row] + dot(h_prev[b,:], Whh[row,:]); gates -> c,h.
__global__ __launch_bounds__(256) void k_lstm_step(
    const float* __restrict__ zx_f, const float* __restrict__ zx_b,
    const float* __restrict__ Whh_f, const float* __restrict__ Whh_b,
    float* __restrict__ hcat, float* __restrict__ cbuf,
    int t, int first)
{
    __shared__ float Wl[16][516];     // 16 gate rows x 512 (+4 pad)
    __shared__ float zb[NB][17];
    int dir = blockIdx.y;
    int uc  = blockIdx.x;             // hidden-unit chunk (4 units)
    int tid = threadIdx.x;
    const float* zx  = dir ? zx_b  : zx_f;
    const float* Whh = dir ? Whh_b : Whh_f;
    int t_eff  = dir ? (NS-1-t) : t;
    int t_prev = dir ? (t_eff+1) : (t_eff-1);

    int b1 = tid >> 4, r = tid & 15;  // 512 dots = 32 b x 16 rows, 2 per thread
    int b2 = b1 + 16;
    float acc1 = 0.f, acc2 = 0.f;
    if (!first) {
        #pragma unroll
        for (int ii = 0; ii < 8; ii++) {
            int idx = tid + 256*ii;          // 0..2047 float4 slots
            int lr = idx >> 7, f4 = (idx & 127) << 2;
            int grow = (lr >> 2)*NH + uc*4 + (lr & 3);
            float4 v = *(const float4*)(Whh + (size_t)grow*NH + f4);
            *(float4*)&Wl[lr][f4] = v;
        }
        __syncthreads();
        const float* h1p = hcat + ((size_t)(b1*NS + t_prev))*NIN1 + dir*NH;
        const float* h2p = hcat + ((size_t)(b2*NS + t_prev))*NIN1 + dir*NH;
        #pragma unroll 4
        for (int k = 0; k < NH; k += 4) {
            float4 w  = *(const float4*)&Wl[r][k];
            float4 ha = *(const float4*)(h1p + k);
            float4 hb = *(const float4*)(h2p + k);
            acc1 += w.x*ha.x + w.y*ha.y + w.z*ha.z + w.w*ha.w;
            acc2 += w.x*hb.x + w.y*hb.y + w.z*hb.z + w.w*hb.w;
        }
    }
    int grow = (r >> 2)*NH + uc*4 + (r & 3);
    zb[b1][r] = zx[((size_t)(b1*NS + t_eff))*NG4 + grow] + acc1;
    zb[b2][r] = zx[((size_t)(b2*NS + t_eff))*NG4 + grow] + acc2;
    __syncthreads();
    if (tid < 128) {
        int b = tid >> 2, ui = tid & 3;
        int unit = uc*4 + ui;
        float zi = zb[b][ui], zf = zb[b][4+ui], zg = zb[b][8+ui], zo = zb[b][12+ui];
        float* cp = cbuf + ((size_t)(dir*NB + b))*NH + unit;
        float cold = first ? 0.f : *cp;
        float cn = sigmoidf_(zf)*cold + sigmoidf_(zi)*tanhf(zg);
        float hn = sigmoidf_(zo)*tanhf(cn);
        *cp = cn;
        hcat[((size_t)(b*NS + t_eff))*NIN1 + dir*NH + unit] = hn;
    }
}

// ---------------- emissions: em = hid1 @ lin2W^T + b2 ----------------
__global__ __launch_bounds__(256) void k_lin2(const float* __restrict__ hid,
    const float* __restrict__ W2, const float* __restrict__ b2, float* __restrict__ em)
{
    int flat = blockIdx.x*256 + threadIdx.x;
    if (flat >= NBS*NT) return;
    int m = flat / NT, j = flat % NT;
    const float* hr = hid + (size_t)m*NHID;
    const float* wr = W2 + j*NHID;
    float acc = b2[j];
    #pragma unroll 8
    for (int k = 0; k < NHID; k += 4) {
        float4 h4 = *(const float4*)(hr+k);
        float4 w4 = *(const float4*)(wr+k);
        acc += h4.x*w4.x + h4.y*w4.y + h4.z*w4.z + h4.w*w4.w;
    }
    em[flat] = acc;
}

// ---------------- viterbi decode (one wave per batch item) ----------------
__global__ __launch_bounds__(64) void k_viterbi(const float* __restrict__ em,
    const float* __restrict__ start, const float* __restrict__ endv,
    const float* __restrict__ trans, float* __restrict__ dec)
{
    __shared__ float sc[NT];
    __shared__ float tr[NT][NT];
    __shared__ unsigned char hist[NS][NT];
    int b = blockIdx.x, tid = threadIdx.x;
    for (int i = tid; i < NT*NT; i += 64) tr[i/NT][i%NT] = trans[i];
    if (tid < NT) sc[tid] = start[tid] + em[((size_t)b*NS)*NT + tid];
    __syncthreads();
    for (int t = 1; t < NS; t++) {
        float best = -1e30f; int bi = 0;
        if (tid < NT) {
            for (int i = 0; i < NT; i++) {
                float v = sc[i] + tr[i][tid];
                if (v > best) { best = v; bi = i; }   // strict > = first max (jnp.argmax)
            }
            hist[t][tid] = (unsigned char)bi;
            best += em[((size_t)b*NS + t)*NT + tid];
        }
        __syncthreads();
        if (tid < NT) sc[tid] = best;
        __syncthreads();
    }
    if (tid == 0) {
        float bv = sc[0] + endv[0]; int tag = 0;
        for (int j = 1; j < NT; j++) { float v = sc[j] + endv[j]; if (v > bv) { bv = v; tag = j; } }
        dec[b*NS + NS-1] = (float)tag;
        for (int t = NS-1; t >= 1; t--) { tag = hist[t][tag]; dec[b*NS + t-1] = (float)tag; }
    }
}

// ---------------- CRF NLL (mask is all ones) ----------------
__global__ __launch_bounds__(64) void k_nll(const float* __restrict__ em,
    const int* __restrict__ tags, const float* __restrict__ start,
    const float* __restrict__ endv, const float* __restrict__ trans,
    float* __restrict__ partial)
{
    __shared__ float sc[NT];
    __shared__ float tr[NT][NT];
    int b = blockIdx.x, tid = threadIdx.x;
    for (int i = tid; i < NT*NT; i += 64) tr[i/NT][i%NT] = trans[i];
    if (tid < NT) sc[tid] = start[tid] + em[((size_t)b*NS)*NT + tid];
    __syncthreads();
    for (int t = 1; t < NS; t++) {
        float nv = 0.f;
        if (tid < NT) {
            float m = -1e30f;
            for (int i = 0; i < NT; i++) m = fmaxf(m, sc[i] + tr[i][tid]);
            float s = 0.f;
            for (int i = 0; i < NT; i++) s += expf(sc[i] + tr[i][tid] - m);
            nv = m + logf(s) + em[((size_t)b*NS + t)*NT + tid];
        }
        __syncthreads();
        if (tid < NT) sc[tid] = nv;
        __syncthreads();
    }
    if (tid == 0) {
        float m = -1e30f;
        for (int j = 0; j < NT; j++) m = fmaxf(m, sc[j] + endv[j]);
        float s = 0.f;
        for (int j = 0; j < NT; j++) s += expf(sc[j] + endv[j] - m);
        float logZ = m + logf(s);
        const int* tg = tags + b*NS;
        float num = start[tg[0]] + em[((size_t)b*NS)*NT + tg[0]];
        for (int t = 1; t < NS; t++)
            num += tr[tg[t-1]][tg[t]] + em[((size_t)b*NS + t)*NT + tg[t]];
        num += endv[tg[NS-1]];
        partial[b] = -(num - logZ);
    }
}

__global__ void k_loss_final(const float* __restrict__ partial, float* __restrict__ loss)
{
    if (threadIdx.x == 0 && blockIdx.x == 0) {
        float s = 0.f;
        for (int b = 0; b < NB; b++) s += partial[b];
        *loss = s / (float)(NB*NS);
    }
}

extern "C" void kernel_launch(void* const* d_in, const int* in_sizes, int n_in,
                              void* d_out, int out_size, void* d_ws, size_t ws_size,
                              hipStream_t stream)
{
    const int*   x_word = (const int*)d_in[0];
    const float* x_pos  = (const float*)d_in[1];
    const int*   x_char = (const int*)d_in[2];
    const float* x_enr  = (const float*)d_in[3];
    // d_in[4] = mask: all ones in this problem, ignored
    const int*   y_word = (const int*)d_in[5];
    const float* wembW  = (const float*)d_in[6];
    const float* cembW  = (const float*)d_in[7];
    const float* cnnW   = (const float*)d_in[8];
    const float* cnnb   = (const float*)d_in[9];
    const float* lin1W  = (const float*)d_in[10];
    const float* lin1b  = (const float*)d_in[11];
    const float* lin2W  = (const float*)d_in[12];
    const float* lin2b  = (const float*)d_in[13];
    const float* crf_s  = (const float*)d_in[14];
    const float* crf_e  = (const float*)d_in[15];
    const float* crf_tr = (const float*)d_in[16];
    const float* l0f_Wih = (const float*)d_in[17];
    const float* l0f_Whh = (const float*)d_in[18];
    const float* l0f_b   = (const float*)d_in[19];
    const float* l0b_Wih = (const float*)d_in[20];
    const float* l0b_Whh = (const float*)d_in[21];
    const float* l0b_b   = (const float*)d_in[22];
    const float* l1f_Wih = (const float*)d_in[23];
    const float* l1f_Whh = (const float*)d_in[24];
    const float* l1f_b   = (const float*)d_in[25];
    const float* l1b_Wih = (const float*)d_in[26];
    const float* l1b_Whh = (const float*)d_in[27];
    const float* l1b_b   = (const float*)d_in[28];

    float* ws = (float*)d_ws;
    size_t off = 0;
    float* xw   = ws + off; off += (size_t)NBS*NIN0P;   // 2.75M
    float* wpf  = ws + off; off += (size_t)NG4*NIN0P;   // 0.69M
    float* wpb  = ws + off; off += (size_t)NG4*NIN0P;   // 0.69M
    float* zxf  = ws + off; off += (size_t)NBS*NG4;     // 16.8M
    float* zxb  = ws + off; off += (size_t)NBS*NG4;     // 16.8M
    float* h0   = ws + off; off += (size_t)NBS*NIN1;    // 8.4M
    float* h1   = ws + off; off += (size_t)NBS*NIN1;    // 8.4M
    float* cbuf = ws + off; off += (size_t)2*NB*NH;     // 32K
    float* hid1 = ws + off; off += (size_t)NBS*NHID;    // 1.0M
    float* partial = ws + off; off += 64;

    float* em_out   = (float*)d_out;
    float* dec_out  = em_out + (size_t)NBS*NT;
    float* loss_out = dec_out + NBS;

    // 1. pad layer-0 input weights to K=336
    k_pad_wih<<<dim3((NG4*NIN0P+255)/256, 2), 256, 0, stream>>>(l0f_Wih, l0b_Wih, wpf, wpb);
    // 2. features
    k_features<<<NBS, 128, 0, stream>>>(x_word, x_pos, x_char, x_enr, wembW, cembW, cnnW, cnnb, xw);
    // 3. layer-0 input projections
    k_gemm<<<dim3(NBS/GBM, NG4/GBN), 256, 0, stream>>>(xw, wpf, l0f_b, zxf, NBS, NG4, NIN0P);
    k_gemm<<<dim3(NBS/GBM, NG4/GBN), 256, 0, stream>>>(xw, wpb, l0b_b, zxb, NBS, NG4, NIN0P);
    // 4. layer-0 recurrence (fwd + bwd per launch)
    for (int t = 0; t < NS; t++)
        k_lstm_step<<<dim3(128,2), 256, 0, stream>>>(zxf, zxb, l0f_Whh, l0b_Whh, h0, cbuf, t, t==0);
    // 5. layer-1 input projections (reuse zx buffers)
    k_gemm<<<dim3(NBS/GBM, NG4/GBN), 256, 0, stream>>>(h0, l1f_Wih, l1f_b, zxf, NBS, NG4, NIN1);
    k_gemm<<<dim3(NBS/GBM, NG4/GBN), 256, 0, stream>>>(h0, l1b_Wih, l1b_b, zxb, NBS, NG4, NIN1);
    // 6. layer-1 recurrence
    for (int t = 0; t < NS; t++)
        k_lstm_step<<<dim3(128,2), 256, 0, stream>>>(zxf, zxb, l1f_Whh, l1b_Whh, h1, cbuf, t, t==0);
    // 7. head
    k_gemm<<<dim3(NBS/GBM, NHID/GBN), 256, 0, stream>>>(h1, lin1W, lin1b, hid1, NBS, NHID, NIN1);
    k_lin2<<<(NBS*NT+255)/256, 256, 0, stream>>>(hid1, lin2W, lin2b, em_out);
    // 8. CRF
    k_viterbi<<<NB, 64, 0, stream>>>(em_out, crf_s, crf_e, crf_tr, dec_out);
    k_nll<<<NB, 64, 0, stream>>>(em_out, y_word, crf_s, crf_e, crf_tr, partial);
    k_loss_final<<<1, 64, 0, stream>>>(partial, loss_out);
}